// Round 8
// baseline (553.291 us; speedup 1.0000x reference)
//
#include <hip/hip_runtime.h>
#include <hip/hip_fp16.h>

#define Nn 50000
#define Ee 800000
#define HD 128        // D == H == 128
#define Ll 3
#define Gg 128
#define Cc 10
#define BN_EPS 1e-5f
#define NBLK1 782     // ceil(Nn/64) — gemm row-tiles
#define NPART 1564    // NBLK1*2 — BN partial slots (per row-half)
#define PPAD 1600     // padded partial stride (feature-major layout)
#define NSCB 49       // ceil(Nn/1024) — scan blocks

typedef __attribute__((ext_vector_type(8))) __bf16 bf16x8;
typedef __attribute__((ext_vector_type(4))) __bf16 bf16x4;
typedef __attribute__((ext_vector_type(4))) float f32x4;

// ----------------------------- CSR build ------------------------------------
__global__ void k_deg(const int* __restrict__ dst, int* __restrict__ deg) {
  int i = blockIdx.x * blockDim.x + threadIdx.x;
  int base = i * 4;
  if (base >= Ee) return;
#pragma unroll
  for (int j = 0; j < 4; ++j) {
    int e = base + j;
    if (e < Ee) atomicAdd(&deg[dst[e]], 1);
  }
}

__global__ void k_scan1(const int* __restrict__ deg, int* __restrict__ offs,
                        int* __restrict__ bsum) {
  __shared__ int b0[1024], b1[1024];
  int tid = threadIdx.x;
  int i = blockIdx.x * 1024 + tid;
  int v = (i < Nn) ? deg[i] : 0;
  int* cur = b0; int* nxt = b1;
  cur[tid] = v;
  __syncthreads();
  for (int off = 1; off < 1024; off <<= 1) {
    int s = cur[tid] + ((tid >= off) ? cur[tid - off] : 0);
    nxt[tid] = s;
    __syncthreads();
    int* t = cur; cur = nxt; nxt = t;
  }
  if (i < Nn) offs[i] = cur[tid] - v;          // exclusive within block
  if (tid == 1023) bsum[blockIdx.x] = cur[1023];
}

__global__ void k_scan2(const int* __restrict__ bsum, int* __restrict__ carry) {
  int lane = threadIdx.x;                      // 64 threads, one wave
  int v = (lane < NSCB) ? bsum[lane] : 0;
  int s = v;
  for (int off = 1; off < 64; off <<= 1) {
    int t = __shfl_up(s, off, 64);
    if (lane >= off) s += t;
  }
  if (lane < NSCB) carry[lane] = s - v;        // exclusive carry per block
}

__global__ void k_scan3(const int* __restrict__ carry, int* __restrict__ offs,
                        int* __restrict__ cursor) {
  int i = blockIdx.x * 1024 + threadIdx.x;
  if (i < Nn) {
    int o = offs[i] + carry[blockIdx.x];
    offs[i] = o; cursor[i] = o;
  }
  if (i == 0) offs[Nn] = Ee;
}

// packed edge fill: (src:16 | fp16 weight:16) = 4B/edge, 4 chains in flight
__global__ void k_fill(const int* __restrict__ src, const int* __restrict__ dst,
                       const float* __restrict__ ec, int* __restrict__ cursor,
                       unsigned int* __restrict__ epk) {
  int i = blockIdx.x * blockDim.x + threadIdx.x;
  int base = i * 4;
  if (base >= Ee) return;
  int d[4], s[4], p[4]; unsigned short hb[4]; bool ok[4];
#pragma unroll
  for (int j = 0; j < 4; ++j) {
    int e = base + j;
    ok[j] = e < Ee;
    if (ok[j]) {
      d[j] = dst[e]; s[j] = src[e];
      hb[j] = __half_as_ushort(__float2half(ec[e]));
    }
  }
#pragma unroll
  for (int j = 0; j < 4; ++j)
    if (ok[j]) p[j] = atomicAdd(&cursor[d[j]], 1);
#pragma unroll
  for (int j = 0; j < 4; ++j)
    if (ok[j]) epk[p[j]] = ((unsigned int)s[j] << 16) | hb[j];
}

// ---- x -> bf16 copy (layer-0 activation stream) ----------------------------
__global__ void k_xcast(const float* __restrict__ x, __bf16* __restrict__ xb) {
  int i = blockIdx.x * blockDim.x + threadIdx.x;
  int stride = gridDim.x * blockDim.x;
  const int n4 = Nn * 32;                      // Nn*128/4
  for (int t = i; t < n4; t += stride) {
    f32x4 v = ((const f32x4*)x)[t];
    bf16x4 b;
#pragma unroll
    for (int j = 0; j < 4; ++j) b[j] = (__bf16)v[j];
    ((bf16x4*)xb)[t] = b;
  }
}

// ---- W prep: Wt_hi/lo[n][k] bf16 split of W[k][n], 6 matrices (3xW1,3xW2) --
__global__ void k_wprep(const float* __restrict__ W1, const float* __restrict__ W2,
                        __bf16* __restrict__ wtHi, __bf16* __restrict__ wtLo) {
  int mat = blockIdx.x >> 3;                    // 0..5
  int chunk = blockIdx.x & 7;                   // 0..7 (2048 elems each)
  const float* W = (mat < 3) ? (W1 + mat * 16384) : (W2 + (mat - 3) * 16384);
  __bf16* hi = wtHi + mat * 16384;
  __bf16* lo = wtLo + mat * 16384;
  for (int t = threadIdx.x; t < 2048; t += blockDim.x) {
    int idx = chunk * 2048 + t;                 // Wt index: n*128 + k
    int n = idx >> 7, k = idx & 127;
    float v = W[k * 128 + n];
    __bf16 h = (__bf16)v;
    hi[idx] = h;
    lo[idx] = (__bf16)(v - (float)h);
  }
}

// -------------------- aggregation: gather (one wave per node) ---------------
// bf16 rows (256B/row), packed 4B edges, 4-edge unroll, fp32 accumulate.
__global__ void k_agg(const __bf16* __restrict__ xb, const int* __restrict__ offs,
                      const unsigned int* __restrict__ epk, float* __restrict__ agg) {
  int wid = threadIdx.x >> 6, lane = threadIdx.x & 63;
  int n = blockIdx.x * 4 + wid;
  if (n >= Nn) return;
  int beg = offs[n], end = offs[n + 1];
  const unsigned int* x2 = (const unsigned int*)xb;   // 2 bf16 per uint, row=64
  float ax0 = 0.f, ay0 = 0.f, ax1 = 0.f, ay1 = 0.f;
  float ax2 = 0.f, ay2 = 0.f, ax3 = 0.f, ay3 = 0.f;
  int j = beg;
  for (; j + 3 < end; j += 4) {
    unsigned int e0 = epk[j], e1 = epk[j + 1], e2 = epk[j + 2], e3 = epk[j + 3];
    unsigned int v0 = x2[(e0 >> 16) * 64 + lane];
    unsigned int v1 = x2[(e1 >> 16) * 64 + lane];
    unsigned int v2 = x2[(e2 >> 16) * 64 + lane];
    unsigned int v3 = x2[(e3 >> 16) * 64 + lane];
    __half_raw h0, h1, h2, h3;
    h0.x = (unsigned short)(e0 & 0xffffu); h1.x = (unsigned short)(e1 & 0xffffu);
    h2.x = (unsigned short)(e2 & 0xffffu); h3.x = (unsigned short)(e3 & 0xffffu);
    float w0 = __half2float(h0), w1 = __half2float(h1);
    float w2 = __half2float(h2), w3 = __half2float(h3);
    ax0 = fmaf(__uint_as_float(v0 << 16), w0, ax0);
    ay0 = fmaf(__uint_as_float(v0 & 0xffff0000u), w0, ay0);
    ax1 = fmaf(__uint_as_float(v1 << 16), w1, ax1);
    ay1 = fmaf(__uint_as_float(v1 & 0xffff0000u), w1, ay1);
    ax2 = fmaf(__uint_as_float(v2 << 16), w2, ax2);
    ay2 = fmaf(__uint_as_float(v2 & 0xffff0000u), w2, ay2);
    ax3 = fmaf(__uint_as_float(v3 << 16), w3, ax3);
    ay3 = fmaf(__uint_as_float(v3 & 0xffff0000u), w3, ay3);
  }
  for (; j < end; ++j) {
    unsigned int e = epk[j];
    unsigned int v = x2[(e >> 16) * 64 + lane];
    __half_raw h; h.x = (unsigned short)(e & 0xffffu);
    float w = __half2float(h);
    ax0 = fmaf(__uint_as_float(v << 16), w, ax0);
    ay0 = fmaf(__uint_as_float(v & 0xffff0000u), w, ay0);
  }
  float2 acc = make_float2(ax0 + ax1 + ax2 + ax3, ay0 + ay1 + ay2 + ay3);
  ((float2*)agg)[n * 64 + lane] = acc;
}

// ---------------- MFMA hi/lo split helpers ----------------------------------
__device__ __forceinline__ void split8(const float* a, bf16x8& hi, bf16x8& lo) {
#pragma unroll
  for (int j = 0; j < 8; ++j) {
    float v = a[j];
    __bf16 h = (__bf16)v;
    hi[j] = h;
    lo[j] = (__bf16)(v - (float)h);
  }
}

// ------ GEMM1 (MFMA, 4 waves): h1 = (agg*nc + xb) @ W1 + b1, + BN stats -----
// 256 thr = 4 waves; block tile 64x128; wave tile 32x64 (wr=row-half,
// wc=col-half): 2m x 4n tiles of 16x16x32. hi/lo split: 3 MFMA per tile/k.
__launch_bounds__(256)
__global__ void k_gemm1(const float* __restrict__ agg, const float* __restrict__ nc,
                        const __bf16* __restrict__ xb,
                        const __bf16* __restrict__ wtHi, const __bf16* __restrict__ wtLo,
                        const float* __restrict__ bias, float* __restrict__ out,
                        float* __restrict__ partial) {
  int tid = threadIdx.x;
  int w = tid >> 6, l = tid & 63;
  int wr = w >> 1, wc = w & 1;
  int row0 = blockIdx.x * 64 + wr * 32;
  int l15 = l & 15, lg = l >> 4;
  int colw = wc * 64;
  int krow = lg * 8;

  f32x4 acc[2][4];
#pragma unroll
  for (int m = 0; m < 2; ++m)
#pragma unroll
    for (int n = 0; n < 4; ++n) acc[m][n] = (f32x4){0.f, 0.f, 0.f, 0.f};

  int rowA[2]; bool rv[2]; float ncv[2];
#pragma unroll
  for (int m = 0; m < 2; ++m) {
    rowA[m] = row0 + m * 16 + l15;
    rv[m] = rowA[m] < Nn;
    ncv[m] = rv[m] ? nc[rowA[m]] : 0.f;
  }

#pragma unroll
  for (int ks = 0; ks < 4; ++ks) {
    int k0 = ks * 32 + krow;
    bf16x8 aHi[2], aLo[2];
#pragma unroll
    for (int m = 0; m < 2; ++m) {
      float av[8];
      if (rv[m]) {
        const float* ap = agg + rowA[m] * 128 + k0;
        bf16x8 xv = *(const bf16x8*)(xb + rowA[m] * 128 + k0);
        f32x4 g0 = *(const f32x4*)ap, g1 = *(const f32x4*)(ap + 4);
#pragma unroll
        for (int jj = 0; jj < 4; ++jj) {
          av[jj]     = fmaf(g0[jj], ncv[m], (float)xv[jj]);
          av[4 + jj] = fmaf(g1[jj], ncv[m], (float)xv[4 + jj]);
        }
      } else {
#pragma unroll
        for (int jj = 0; jj < 8; ++jj) av[jj] = 0.f;
      }
      split8(av, aHi[m], aLo[m]);
    }
    bf16x8 bHi[4], bLo[4];
#pragma unroll
    for (int n = 0; n < 4; ++n) {
      int c = colw + n * 16 + l15;
      bHi[n] = *(const bf16x8*)(wtHi + c * 128 + k0);
      bLo[n] = *(const bf16x8*)(wtLo + c * 128 + k0);
    }
#pragma unroll
    for (int m = 0; m < 2; ++m)
#pragma unroll
      for (int n = 0; n < 4; ++n) {
        acc[m][n] = __builtin_amdgcn_mfma_f32_16x16x32_bf16(aHi[m], bHi[n], acc[m][n], 0, 0, 0);
        acc[m][n] = __builtin_amdgcn_mfma_f32_16x16x32_bf16(aLo[m], bHi[n], acc[m][n], 0, 0, 0);
        acc[m][n] = __builtin_amdgcn_mfma_f32_16x16x32_bf16(aHi[m], bLo[n], acc[m][n], 0, 0, 0);
      }
  }

  // epilogue: bias, store, BN column stats (this wave's 32-row half)
  float s[4] = {0.f, 0.f, 0.f, 0.f}, q[4] = {0.f, 0.f, 0.f, 0.f};
#pragma unroll
  for (int n = 0; n < 4; ++n) {
    int c = colw + n * 16 + l15;
    float bv = bias[c];
#pragma unroll
    for (int m = 0; m < 2; ++m) {
      int rbase = row0 + m * 16 + lg * 4;
#pragma unroll
      for (int r = 0; r < 4; ++r) {
        int rr = rbase + r;
        if (rr < Nn) {
          float o = acc[m][n][r] + bv;
          out[rr * 128 + c] = o;
          s[n] += o; q[n] += o * o;
        }
      }
    }
  }
#pragma unroll
  for (int n = 0; n < 4; ++n) {
    s[n] += __shfl_xor(s[n], 16, 64); q[n] += __shfl_xor(q[n], 16, 64);
    s[n] += __shfl_xor(s[n], 32, 64); q[n] += __shfl_xor(q[n], 32, 64);
  }
  if (lg == 0) {
    int slot = blockIdx.x * 2 + wr;
#pragma unroll
    for (int n = 0; n < 4; ++n) {
      int f = colw + n * 16 + l15;
      partial[f * PPAD + slot] = s[n];
      partial[(128 + f) * PPAD + slot] = q[n];
    }
  }
}

// parallel partial reduce: one block per feature, coalesced strided reads.
__global__ void k_bnfin(const float* __restrict__ partial,
                        const float* __restrict__ g1, const float* __restrict__ be1,
                        float* __restrict__ scaleA, float* __restrict__ shiftA) {
  __shared__ float ss[256], qq[256];
  int f = blockIdx.x, t = threadIdx.x;
  float s = 0.f, q = 0.f;
  for (int b = t; b < NPART; b += 256) {
    s += partial[f * PPAD + b];
    q += partial[(128 + f) * PPAD + b];
  }
  ss[t] = s; qq[t] = q;
  __syncthreads();
  for (int off = 128; off > 0; off >>= 1) {
    if (t < off) { ss[t] += ss[t + off]; qq[t] += qq[t + off]; }
    __syncthreads();
  }
  if (t == 0) {
    const float inv = 1.0f / (float)Nn;
    float mu = ss[0] * inv;
    float var = fmaxf(qq[0] * inv - mu * mu, 0.f);
    float rs = rsqrtf(var + BN_EPS);
    float sc = rs * g1[f];
    scaleA[f] = sc;
    shiftA[f] = be1[f] - mu * sc;
  }
}

// ---- GEMM2 (MFMA, 4 waves): xb = bf16(relu( relu(h1*sc+sh) @ W2 + b2 )) ----
__launch_bounds__(256)
__global__ void k_gemm2(const float* __restrict__ h1, const float* __restrict__ scaleA,
                        const float* __restrict__ shiftA,
                        const __bf16* __restrict__ wtHi, const __bf16* __restrict__ wtLo,
                        const float* __restrict__ bias, __bf16* __restrict__ xbout) {
  int tid = threadIdx.x;
  int w = tid >> 6, l = tid & 63;
  int wr = w >> 1, wc = w & 1;
  int row0 = blockIdx.x * 64 + wr * 32;
  int l15 = l & 15, lg = l >> 4;
  int colw = wc * 64;
  int krow = lg * 8;

  f32x4 acc[2][4];
#pragma unroll
  for (int m = 0; m < 2; ++m)
#pragma unroll
    for (int n = 0; n < 4; ++n) acc[m][n] = (f32x4){0.f, 0.f, 0.f, 0.f};

  int rowA[2]; bool rv[2];
#pragma unroll
  for (int m = 0; m < 2; ++m) {
    rowA[m] = row0 + m * 16 + l15;
    rv[m] = rowA[m] < Nn;
  }

#pragma unroll
  for (int ks = 0; ks < 4; ++ks) {
    int k0 = ks * 32 + krow;
    f32x4 sc0 = *(const f32x4*)(scaleA + k0), sc1 = *(const f32x4*)(scaleA + k0 + 4);
    f32x4 sh0 = *(const f32x4*)(shiftA + k0), sh1 = *(const f32x4*)(shiftA + k0 + 4);
    bf16x8 aHi[2], aLo[2];
#pragma unroll
    for (int m = 0; m < 2; ++m) {
      float av[8];
      if (rv[m]) {
        const float* hp = h1 + rowA[m] * 128 + k0;
        f32x4 h0 = *(const f32x4*)hp, h1v = *(const f32x4*)(hp + 4);
#pragma unroll
        for (int jj = 0; jj < 4; ++jj) {
          av[jj]     = fmaxf(fmaf(h0[jj],  sc0[jj], sh0[jj]), 0.f);
          av[4 + jj] = fmaxf(fmaf(h1v[jj], sc1[jj], sh1[jj]), 0.f);
        }
      } else {
#pragma unroll
        for (int jj = 0; jj < 8; ++jj) av[jj] = 0.f;
      }
      split8(av, aHi[m], aLo[m]);
    }
    bf16x8 bHi[4], bLo[4];
#pragma unroll
    for (int n = 0; n < 4; ++n) {
      int c = colw + n * 16 + l15;
      bHi[n] = *(const bf16x8*)(wtHi + c * 128 + k0);
      bLo[n] = *(const bf16x8*)(wtLo + c * 128 + k0);
    }
#pragma unroll
    for (int m = 0; m < 2; ++m)
#pragma unroll
      for (int n = 0; n < 4; ++n) {
        acc[m][n] = __builtin_amdgcn_mfma_f32_16x16x32_bf16(aHi[m], bHi[n], acc[m][n], 0, 0, 0);
        acc[m][n] = __builtin_amdgcn_mfma_f32_16x16x32_bf16(aLo[m], bHi[n], acc[m][n], 0, 0, 0);
        acc[m][n] = __builtin_amdgcn_mfma_f32_16x16x32_bf16(aHi[m], bLo[n], acc[m][n], 0, 0, 0);
      }
  }

#pragma unroll
  for (int n = 0; n < 4; ++n) {
    int c = colw + n * 16 + l15;
    float bv = bias[c];
#pragma unroll
    for (int m = 0; m < 2; ++m) {
      int rbase = row0 + m * 16 + lg * 4;
#pragma unroll
      for (int r = 0; r < 4; ++r) {
        int rr = rbase + r;
        if (rr < Nn) xbout[rr * 128 + c] = (__bf16)fmaxf(acc[m][n][r] + bv, 0.f);
      }
    }
  }
}

// ------------------------------ pooling (bf16 input) ------------------------
#define PCH 64
__global__ void k_pool(const __bf16* __restrict__ xb, const int* __restrict__ batch,
                       float* __restrict__ pooled, float* __restrict__ gcnt) {
  int wid = threadIdx.x >> 6, lane = threadIdx.x & 63;
  int w = blockIdx.x * 4 + wid;
  int n0 = w * PCH;
  if (n0 >= Nn) return;
  int n1 = (n0 + PCH < Nn) ? n0 + PCH : Nn;
  const unsigned int* x2 = (const unsigned int*)xb;
  float2 acc = make_float2(0.f, 0.f);
  int cur = batch[n0];
  int cnt = 0;
  for (int n = n0; n < n1; ++n) {
    int g = batch[n];                    // wave-uniform
    if (g != cur) {
      atomicAdd(&pooled[cur * 128 + lane * 2 + 0], acc.x);
      atomicAdd(&pooled[cur * 128 + lane * 2 + 1], acc.y);
      if (lane == 0) atomicAdd(&gcnt[cur], (float)cnt);
      acc = make_float2(0.f, 0.f); cnt = 0; cur = g;
    }
    unsigned int v = x2[n * 64 + lane];
    acc.x += __uint_as_float(v << 16);
    acc.y += __uint_as_float(v & 0xffff0000u);
    ++cnt;
  }
  atomicAdd(&pooled[cur * 128 + lane * 2 + 0], acc.x);
  atomicAdd(&pooled[cur * 128 + lane * 2 + 1], acc.y);
  if (lane == 0) atomicAdd(&gcnt[cur], (float)cnt);
}

__global__ void k_head(const float* __restrict__ pooled, const float* __restrict__ gcnt,
                       const float* __restrict__ Wc, const float* __restrict__ bc,
                       float* __restrict__ out) {
  __shared__ float p[128];
  int g = blockIdx.x, tid = threadIdx.x;
  p[tid] = pooled[g * 128 + tid] / fmaxf(gcnt[g], 1.0f);
  __syncthreads();
  if (tid < Cc) {
    float acc = bc[tid];
    for (int k = 0; k < 128; ++k) acc = fmaf(p[k], Wc[k * Cc + tid], acc);
    out[g * Cc + tid] = acc;
  }
}

// ------------------------------ launcher ------------------------------------
extern "C" void kernel_launch(void* const* d_in, const int* in_sizes, int n_in,
                              void* d_out, int out_size, void* d_ws, size_t ws_size,
                              hipStream_t stream) {
  const float* x    = (const float*)d_in[0];
  const float* ncn  = (const float*)d_in[1];
  const float* ecn  = (const float*)d_in[2];
  const float* W1   = (const float*)d_in[3];
  const float* b1   = (const float*)d_in[4];
  const float* g1   = (const float*)d_in[5];
  const float* be1  = (const float*)d_in[6];
  const float* W2   = (const float*)d_in[7];
  const float* b2   = (const float*)d_in[8];
  const float* Wc   = (const float*)d_in[9];
  const float* bc   = (const float*)d_in[10];
  const int*   ei   = (const int*)d_in[11];
  const int*   batch= (const int*)d_in[12];
  const int* src  = ei;
  const int* dstp = ei + Ee;

  float* fws = (float*)d_ws;
  float* agg      = fws;                       // N*128 fp32
  float* h1       = fws +  6400000;            // N*128 fp32
  float* partial  = fws + 12800000;            // 256*PPAD (1.6 MB)
  float* scaleA   = partial + 256 * PPAD;      // 128
  float* shiftA   = scaleA + 128;              // 128
  float* pooled   = shiftA + 128;              // G*128
  float* gcnt     = pooled + Gg * 128;         // 128
  int*   deg      = (int*)(gcnt + 128);        // N
  int*   offs     = deg + Nn;                  // N+64
  int*   cursor   = offs + Nn + 64;            // N
  int*   bsum     = cursor + Nn;               // 64
  int*   carry    = bsum + 64;                 // 64
  unsigned int* epk = (unsigned int*)(carry + 64); // E (4B packed edges)
  __bf16* wtHi    = (__bf16*)(epk + Ee);       // 6*16384 bf16
  __bf16* wtLo    = wtHi + 6 * 16384;          // 6*16384 bf16
  __bf16* xb      = wtLo + 6 * 16384;          // N*128 bf16 (12.8 MB)

  // W prep + x cast + CSR build (once per call, reused by all 3 layers)
  k_wprep<<<48, 256, 0, stream>>>(W1, W2, wtHi, wtLo);
  k_xcast<<<2048, 256, 0, stream>>>(x, xb);
  hipMemsetAsync(deg, 0, Nn * sizeof(int), stream);
  k_deg<<<(Ee / 4 + 255) / 256, 256, 0, stream>>>(dstp, deg);
  k_scan1<<<NSCB, 1024, 0, stream>>>(deg, offs, bsum);
  k_scan2<<<1, 64, 0, stream>>>(bsum, carry);
  k_scan3<<<NSCB, 1024, 0, stream>>>(carry, offs, cursor);
  k_fill<<<(Ee / 4 + 255) / 256, 256, 0, stream>>>(src, dstp, ecn, cursor, epk);

  // bf16 activation stream: xb is both layer input (agg gather + residual)
  // and gemm2 output; stream order makes the single buffer safe.
  for (int l = 0; l < Ll; ++l) {
    k_agg<<<(Nn + 3) / 4, 256, 0, stream>>>(xb, offs, epk, agg);
    k_gemm1<<<NBLK1, 256, 0, stream>>>(agg, ncn, xb,
                                       wtHi + l * 16384, wtLo + l * 16384,
                                       b1 + l * 128, h1, partial);
    k_bnfin<<<128, 256, 0, stream>>>(partial, g1 + l * 128, be1 + l * 128,
                                     scaleA, shiftA);
    k_gemm2<<<NBLK1, 256, 0, stream>>>(h1, scaleA, shiftA,
                                       wtHi + (3 + l) * 16384, wtLo + (3 + l) * 16384,
                                       b2 + l * 128, xb);
  }

  hipMemsetAsync(pooled, 0, (Gg * 128 + 128) * sizeof(float), stream);
  k_pool<<<(Nn + PCH * 4 - 1) / (PCH * 4), 256, 0, stream>>>(xb, batch, pooled, gcnt);
  k_head<<<Gg, 128, 0, stream>>>(pooled, gcnt, Wc, bc, (float*)d_out);
}

// Round 9
// 545.288 us; speedup vs baseline: 1.0147x; 1.0147x over previous
//
#include <hip/hip_runtime.h>
#include <hip/hip_fp16.h>

#define Nn 50000
#define Ee 800000
#define HD 128        // D == H == 128
#define Ll 3
#define Gg 128
#define Cc 10
#define BN_EPS 1e-5f
#define NBLK1 782     // ceil(Nn/64) — gemm row-tiles
#define NPART 1564    // NBLK1*2 — BN partial slots (per row-half)
#define PPAD 1600     // padded partial stride (feature-major layout)
#define NSCB 49       // ceil(Nn/1024) — scan blocks

typedef __attribute__((ext_vector_type(8))) __bf16 bf16x8;
typedef __attribute__((ext_vector_type(4))) __bf16 bf16x4;
typedef __attribute__((ext_vector_type(2))) __bf16 bf16x2;
typedef __attribute__((ext_vector_type(4))) float f32x4;

// ----------------------------- CSR build ------------------------------------
__global__ void k_deg(const int* __restrict__ dst, int* __restrict__ deg) {
  int i = blockIdx.x * blockDim.x + threadIdx.x;
  int base = i * 4;
  if (base >= Ee) return;
#pragma unroll
  for (int j = 0; j < 4; ++j) {
    int e = base + j;
    if (e < Ee) atomicAdd(&deg[dst[e]], 1);
  }
}

__global__ void k_scan1(const int* __restrict__ deg, int* __restrict__ offs,
                        int* __restrict__ bsum) {
  __shared__ int b0[1024], b1[1024];
  int tid = threadIdx.x;
  int i = blockIdx.x * 1024 + tid;
  int v = (i < Nn) ? deg[i] : 0;
  int* cur = b0; int* nxt = b1;
  cur[tid] = v;
  __syncthreads();
  for (int off = 1; off < 1024; off <<= 1) {
    int s = cur[tid] + ((tid >= off) ? cur[tid - off] : 0);
    nxt[tid] = s;
    __syncthreads();
    int* t = cur; cur = nxt; nxt = t;
  }
  if (i < Nn) offs[i] = cur[tid] - v;          // exclusive within block
  if (tid == 1023) bsum[blockIdx.x] = cur[1023];
}

__global__ void k_scan2(const int* __restrict__ bsum, int* __restrict__ carry) {
  int lane = threadIdx.x;                      // 64 threads, one wave
  int v = (lane < NSCB) ? bsum[lane] : 0;
  int s = v;
  for (int off = 1; off < 64; off <<= 1) {
    int t = __shfl_up(s, off, 64);
    if (lane >= off) s += t;
  }
  if (lane < NSCB) carry[lane] = s - v;        // exclusive carry per block
}

__global__ void k_scan3(const int* __restrict__ carry, int* __restrict__ offs,
                        int* __restrict__ cursor) {
  int i = blockIdx.x * 1024 + threadIdx.x;
  if (i < Nn) {
    int o = offs[i] + carry[blockIdx.x];
    offs[i] = o; cursor[i] = o;
  }
  if (i == 0) offs[Nn] = Ee;
}

// packed edge fill: (src:16 | fp16 weight:16) = 4B/edge, 4 chains in flight.
// nt stores: probe whether bypassing write-allocate reduces line thrash.
__global__ void k_fill(const int* __restrict__ src, const int* __restrict__ dst,
                       const float* __restrict__ ec, int* __restrict__ cursor,
                       unsigned int* __restrict__ epk) {
  int i = blockIdx.x * blockDim.x + threadIdx.x;
  int base = i * 4;
  if (base >= Ee) return;
  int d[4], s[4], p[4]; unsigned short hb[4]; bool ok[4];
#pragma unroll
  for (int j = 0; j < 4; ++j) {
    int e = base + j;
    ok[j] = e < Ee;
    if (ok[j]) {
      d[j] = dst[e]; s[j] = src[e];
      hb[j] = __half_as_ushort(__float2half(ec[e]));
    }
  }
#pragma unroll
  for (int j = 0; j < 4; ++j)
    if (ok[j]) p[j] = atomicAdd(&cursor[d[j]], 1);
#pragma unroll
  for (int j = 0; j < 4; ++j)
    if (ok[j]) __builtin_nontemporal_store(((unsigned int)s[j] << 16) | hb[j],
                                           &epk[p[j]]);
}

// ---- x -> bf16 copy (layer-0 activation stream) ----------------------------
__global__ void k_xcast(const float* __restrict__ x, __bf16* __restrict__ xb) {
  int i = blockIdx.x * blockDim.x + threadIdx.x;
  int stride = gridDim.x * blockDim.x;
  const int n4 = Nn * 32;                      // Nn*128/4
  for (int t = i; t < n4; t += stride) {
    f32x4 v = ((const f32x4*)x)[t];
    bf16x4 b;
#pragma unroll
    for (int j = 0; j < 4; ++j) b[j] = (__bf16)v[j];
    ((bf16x4*)xb)[t] = b;
  }
}

// ---- W prep: Wt_hi/lo[n][k] bf16 split of W[k][n], 6 matrices (3xW1,3xW2) --
__global__ void k_wprep(const float* __restrict__ W1, const float* __restrict__ W2,
                        __bf16* __restrict__ wtHi, __bf16* __restrict__ wtLo) {
  int mat = blockIdx.x >> 3;                    // 0..5
  int chunk = blockIdx.x & 7;                   // 0..7 (2048 elems each)
  const float* W = (mat < 3) ? (W1 + mat * 16384) : (W2 + (mat - 3) * 16384);
  __bf16* hi = wtHi + mat * 16384;
  __bf16* lo = wtLo + mat * 16384;
  for (int t = threadIdx.x; t < 2048; t += blockDim.x) {
    int idx = chunk * 2048 + t;                 // Wt index: n*128 + k
    int n = idx >> 7, k = idx & 127;
    float v = W[k * 128 + n];
    __bf16 h = (__bf16)v;
    hi[idx] = h;
    lo[idx] = (__bf16)(v - (float)h);
  }
}

// -------------------- aggregation: gather (one wave per node) ---------------
// bf16 rows, packed 4B edges, 8-edge unroll (8 row-gathers in flight),
// fp32 accumulate, bf16 output (half the write traffic).
__global__ void k_agg(const __bf16* __restrict__ xb, const int* __restrict__ offs,
                      const unsigned int* __restrict__ epk, __bf16* __restrict__ aggb) {
  int wid = threadIdx.x >> 6, lane = threadIdx.x & 63;
  int n = blockIdx.x * 4 + wid;
  if (n >= Nn) return;
  int beg = offs[n], end = offs[n + 1];
  const unsigned int* x2 = (const unsigned int*)xb;   // 2 bf16 per uint, row=64
  float ax[8], ay[8];
#pragma unroll
  for (int t = 0; t < 8; ++t) { ax[t] = 0.f; ay[t] = 0.f; }
  int j = beg;
  for (; j + 7 < end; j += 8) {
    unsigned int e[8], v[8];
#pragma unroll
    for (int t = 0; t < 8; ++t) e[t] = epk[j + t];
#pragma unroll
    for (int t = 0; t < 8; ++t) v[t] = x2[(e[t] >> 16) * 64 + lane];
#pragma unroll
    for (int t = 0; t < 8; ++t) {
      __half_raw h; h.x = (unsigned short)(e[t] & 0xffffu);
      float w = __half2float(h);
      ax[t] = fmaf(__uint_as_float(v[t] << 16), w, ax[t]);
      ay[t] = fmaf(__uint_as_float(v[t] & 0xffff0000u), w, ay[t]);
    }
  }
  for (; j < end; ++j) {
    unsigned int e = epk[j];
    unsigned int v = x2[(e >> 16) * 64 + lane];
    __half_raw h; h.x = (unsigned short)(e & 0xffffu);
    float w = __half2float(h);
    ax[0] = fmaf(__uint_as_float(v << 16), w, ax[0]);
    ay[0] = fmaf(__uint_as_float(v & 0xffff0000u), w, ay[0]);
  }
  float sx = (ax[0] + ax[1]) + (ax[2] + ax[3]) + ((ax[4] + ax[5]) + (ax[6] + ax[7]));
  float sy = (ay[0] + ay[1]) + (ay[2] + ay[3]) + ((ay[4] + ay[5]) + (ay[6] + ay[7]));
  bf16x2 o; o[0] = (__bf16)sx; o[1] = (__bf16)sy;
  ((bf16x2*)aggb)[n * 64 + lane] = o;
}

// ---------------- MFMA hi/lo split helpers ----------------------------------
__device__ __forceinline__ void split8(const float* a, bf16x8& hi, bf16x8& lo) {
#pragma unroll
  for (int j = 0; j < 8; ++j) {
    float v = a[j];
    __bf16 h = (__bf16)v;
    hi[j] = h;
    lo[j] = (__bf16)(v - (float)h);
  }
}

// ------ GEMM1 (MFMA, 4 waves): h1b = bf16((aggb*nc + xb) @ W1 + b1), BN stats
__launch_bounds__(256)
__global__ void k_gemm1(const __bf16* __restrict__ aggb, const float* __restrict__ nc,
                        const __bf16* __restrict__ xb,
                        const __bf16* __restrict__ wtHi, const __bf16* __restrict__ wtLo,
                        const float* __restrict__ bias, __bf16* __restrict__ h1b,
                        float* __restrict__ partial) {
  int tid = threadIdx.x;
  int w = tid >> 6, l = tid & 63;
  int wr = w >> 1, wc = w & 1;
  int row0 = blockIdx.x * 64 + wr * 32;
  int l15 = l & 15, lg = l >> 4;
  int colw = wc * 64;
  int krow = lg * 8;

  f32x4 acc[2][4];
#pragma unroll
  for (int m = 0; m < 2; ++m)
#pragma unroll
    for (int n = 0; n < 4; ++n) acc[m][n] = (f32x4){0.f, 0.f, 0.f, 0.f};

  int rowA[2]; bool rv[2]; float ncv[2];
#pragma unroll
  for (int m = 0; m < 2; ++m) {
    rowA[m] = row0 + m * 16 + l15;
    rv[m] = rowA[m] < Nn;
    ncv[m] = rv[m] ? nc[rowA[m]] : 0.f;
  }

#pragma unroll
  for (int ks = 0; ks < 4; ++ks) {
    int k0 = ks * 32 + krow;
    bf16x8 aHi[2], aLo[2];
#pragma unroll
    for (int m = 0; m < 2; ++m) {
      float av[8];
      if (rv[m]) {
        bf16x8 ag = *(const bf16x8*)(aggb + rowA[m] * 128 + k0);
        bf16x8 xv = *(const bf16x8*)(xb + rowA[m] * 128 + k0);
#pragma unroll
        for (int jj = 0; jj < 8; ++jj)
          av[jj] = fmaf((float)ag[jj], ncv[m], (float)xv[jj]);
      } else {
#pragma unroll
        for (int jj = 0; jj < 8; ++jj) av[jj] = 0.f;
      }
      split8(av, aHi[m], aLo[m]);
    }
    bf16x8 bHi[4], bLo[4];
#pragma unroll
    for (int n = 0; n < 4; ++n) {
      int c = colw + n * 16 + l15;
      bHi[n] = *(const bf16x8*)(wtHi + c * 128 + k0);
      bLo[n] = *(const bf16x8*)(wtLo + c * 128 + k0);
    }
#pragma unroll
    for (int m = 0; m < 2; ++m)
#pragma unroll
      for (int n = 0; n < 4; ++n) {
        acc[m][n] = __builtin_amdgcn_mfma_f32_16x16x32_bf16(aHi[m], bHi[n], acc[m][n], 0, 0, 0);
        acc[m][n] = __builtin_amdgcn_mfma_f32_16x16x32_bf16(aLo[m], bHi[n], acc[m][n], 0, 0, 0);
        acc[m][n] = __builtin_amdgcn_mfma_f32_16x16x32_bf16(aHi[m], bLo[n], acc[m][n], 0, 0, 0);
      }
  }

  // epilogue: bias, bf16 store, BN column stats (fp32, pre-rounding)
  float s[4] = {0.f, 0.f, 0.f, 0.f}, q[4] = {0.f, 0.f, 0.f, 0.f};
#pragma unroll
  for (int n = 0; n < 4; ++n) {
    int c = colw + n * 16 + l15;
    float bv = bias[c];
#pragma unroll
    for (int m = 0; m < 2; ++m) {
      int rbase = row0 + m * 16 + lg * 4;
#pragma unroll
      for (int r = 0; r < 4; ++r) {
        int rr = rbase + r;
        if (rr < Nn) {
          float o = acc[m][n][r] + bv;
          h1b[rr * 128 + c] = (__bf16)o;
          s[n] += o; q[n] += o * o;
        }
      }
    }
  }
#pragma unroll
  for (int n = 0; n < 4; ++n) {
    s[n] += __shfl_xor(s[n], 16, 64); q[n] += __shfl_xor(q[n], 16, 64);
    s[n] += __shfl_xor(s[n], 32, 64); q[n] += __shfl_xor(q[n], 32, 64);
  }
  if (lg == 0) {
    int slot = blockIdx.x * 2 + wr;
#pragma unroll
    for (int n = 0; n < 4; ++n) {
      int f = colw + n * 16 + l15;
      partial[f * PPAD + slot] = s[n];
      partial[(128 + f) * PPAD + slot] = q[n];
    }
  }
}

// parallel partial reduce: one block per feature, coalesced strided reads.
__global__ void k_bnfin(const float* __restrict__ partial,
                        const float* __restrict__ g1, const float* __restrict__ be1,
                        float* __restrict__ scaleA, float* __restrict__ shiftA) {
  __shared__ float ss[256], qq[256];
  int f = blockIdx.x, t = threadIdx.x;
  float s = 0.f, q = 0.f;
  for (int b = t; b < NPART; b += 256) {
    s += partial[f * PPAD + b];
    q += partial[(128 + f) * PPAD + b];
  }
  ss[t] = s; qq[t] = q;
  __syncthreads();
  for (int off = 128; off > 0; off >>= 1) {
    if (t < off) { ss[t] += ss[t + off]; qq[t] += qq[t + off]; }
    __syncthreads();
  }
  if (t == 0) {
    const float inv = 1.0f / (float)Nn;
    float mu = ss[0] * inv;
    float var = fmaxf(qq[0] * inv - mu * mu, 0.f);
    float rs = rsqrtf(var + BN_EPS);
    float sc = rs * g1[f];
    scaleA[f] = sc;
    shiftA[f] = be1[f] - mu * sc;
  }
}

// ---- GEMM2 (MFMA, 4 waves): xb = bf16(relu( relu(h1b*sc+sh) @ W2 + b2 )) ---
__launch_bounds__(256)
__global__ void k_gemm2(const __bf16* __restrict__ h1b, const float* __restrict__ scaleA,
                        const float* __restrict__ shiftA,
                        const __bf16* __restrict__ wtHi, const __bf16* __restrict__ wtLo,
                        const float* __restrict__ bias, __bf16* __restrict__ xbout) {
  int tid = threadIdx.x;
  int w = tid >> 6, l = tid & 63;
  int wr = w >> 1, wc = w & 1;
  int row0 = blockIdx.x * 64 + wr * 32;
  int l15 = l & 15, lg = l >> 4;
  int colw = wc * 64;
  int krow = lg * 8;

  f32x4 acc[2][4];
#pragma unroll
  for (int m = 0; m < 2; ++m)
#pragma unroll
    for (int n = 0; n < 4; ++n) acc[m][n] = (f32x4){0.f, 0.f, 0.f, 0.f};

  int rowA[2]; bool rv[2];
#pragma unroll
  for (int m = 0; m < 2; ++m) {
    rowA[m] = row0 + m * 16 + l15;
    rv[m] = rowA[m] < Nn;
  }

#pragma unroll
  for (int ks = 0; ks < 4; ++ks) {
    int k0 = ks * 32 + krow;
    f32x4 sc0 = *(const f32x4*)(scaleA + k0), sc1 = *(const f32x4*)(scaleA + k0 + 4);
    f32x4 sh0 = *(const f32x4*)(shiftA + k0), sh1 = *(const f32x4*)(shiftA + k0 + 4);
    bf16x8 aHi[2], aLo[2];
#pragma unroll
    for (int m = 0; m < 2; ++m) {
      float av[8];
      if (rv[m]) {
        bf16x8 hv = *(const bf16x8*)(h1b + rowA[m] * 128 + k0);
#pragma unroll
        for (int jj = 0; jj < 4; ++jj) {
          av[jj]     = fmaxf(fmaf((float)hv[jj],     sc0[jj], sh0[jj]), 0.f);
          av[4 + jj] = fmaxf(fmaf((float)hv[4 + jj], sc1[jj], sh1[jj]), 0.f);
        }
      } else {
#pragma unroll
        for (int jj = 0; jj < 8; ++jj) av[jj] = 0.f;
      }
      split8(av, aHi[m], aLo[m]);
    }
    bf16x8 bHi[4], bLo[4];
#pragma unroll
    for (int n = 0; n < 4; ++n) {
      int c = colw + n * 16 + l15;
      bHi[n] = *(const bf16x8*)(wtHi + c * 128 + k0);
      bLo[n] = *(const bf16x8*)(wtLo + c * 128 + k0);
    }
#pragma unroll
    for (int m = 0; m < 2; ++m)
#pragma unroll
      for (int n = 0; n < 4; ++n) {
        acc[m][n] = __builtin_amdgcn_mfma_f32_16x16x32_bf16(aHi[m], bHi[n], acc[m][n], 0, 0, 0);
        acc[m][n] = __builtin_amdgcn_mfma_f32_16x16x32_bf16(aLo[m], bHi[n], acc[m][n], 0, 0, 0);
        acc[m][n] = __builtin_amdgcn_mfma_f32_16x16x32_bf16(aHi[m], bLo[n], acc[m][n], 0, 0, 0);
      }
  }

#pragma unroll
  for (int n = 0; n < 4; ++n) {
    int c = colw + n * 16 + l15;
    float bv = bias[c];
#pragma unroll
    for (int m = 0; m < 2; ++m) {
      int rbase = row0 + m * 16 + lg * 4;
#pragma unroll
      for (int r = 0; r < 4; ++r) {
        int rr = rbase + r;
        if (rr < Nn) xbout[rr * 128 + c] = (__bf16)fmaxf(acc[m][n][r] + bv, 0.f);
      }
    }
  }
}

// ------------------------------ pooling (bf16 input) ------------------------
#define PCH 64
__global__ void k_pool(const __bf16* __restrict__ xb, const int* __restrict__ batch,
                       float* __restrict__ pooled, float* __restrict__ gcnt) {
  int wid = threadIdx.x >> 6, lane = threadIdx.x & 63;
  int w = blockIdx.x * 4 + wid;
  int n0 = w * PCH;
  if (n0 >= Nn) return;
  int n1 = (n0 + PCH < Nn) ? n0 + PCH : Nn;
  const unsigned int* x2 = (const unsigned int*)xb;
  float2 acc = make_float2(0.f, 0.f);
  int cur = batch[n0];
  int cnt = 0;
  for (int n = n0; n < n1; ++n) {
    int g = batch[n];                    // wave-uniform
    if (g != cur) {
      atomicAdd(&pooled[cur * 128 + lane * 2 + 0], acc.x);
      atomicAdd(&pooled[cur * 128 + lane * 2 + 1], acc.y);
      if (lane == 0) atomicAdd(&gcnt[cur], (float)cnt);
      acc = make_float2(0.f, 0.f); cnt = 0; cur = g;
    }
    unsigned int v = x2[n * 64 + lane];
    acc.x += __uint_as_float(v << 16);
    acc.y += __uint_as_float(v & 0xffff0000u);
    ++cnt;
  }
  atomicAdd(&pooled[cur * 128 + lane * 2 + 0], acc.x);
  atomicAdd(&pooled[cur * 128 + lane * 2 + 1], acc.y);
  if (lane == 0) atomicAdd(&gcnt[cur], (float)cnt);
}

__global__ void k_head(const float* __restrict__ pooled, const float* __restrict__ gcnt,
                       const float* __restrict__ Wc, const float* __restrict__ bc,
                       float* __restrict__ out) {
  __shared__ float p[128];
  int g = blockIdx.x, tid = threadIdx.x;
  p[tid] = pooled[g * 128 + tid] / fmaxf(gcnt[g], 1.0f);
  __syncthreads();
  if (tid < Cc) {
    float acc = bc[tid];
    for (int k = 0; k < 128; ++k) acc = fmaf(p[k], Wc[k * Cc + tid], acc);
    out[g * Cc + tid] = acc;
  }
}

// ------------------------------ launcher ------------------------------------
extern "C" void kernel_launch(void* const* d_in, const int* in_sizes, int n_in,
                              void* d_out, int out_size, void* d_ws, size_t ws_size,
                              hipStream_t stream) {
  const float* x    = (const float*)d_in[0];
  const float* ncn  = (const float*)d_in[1];
  const float* ecn  = (const float*)d_in[2];
  const float* W1   = (const float*)d_in[3];
  const float* b1   = (const float*)d_in[4];
  const float* g1   = (const float*)d_in[5];
  const float* be1  = (const float*)d_in[6];
  const float* W2   = (const float*)d_in[7];
  const float* b2   = (const float*)d_in[8];
  const float* Wc   = (const float*)d_in[9];
  const float* bc   = (const float*)d_in[10];
  const int*   ei   = (const int*)d_in[11];
  const int*   batch= (const int*)d_in[12];
  const int* src  = ei;
  const int* dstp = ei + Ee;

  float* fws = (float*)d_ws;
  float* partial  = fws;                       // 256*PPAD (1.6 MB)
  float* scaleA   = partial + 256 * PPAD;      // 128
  float* shiftA   = scaleA + 128;              // 128
  float* pooled   = shiftA + 128;              // G*128
  float* gcnt     = pooled + Gg * 128;         // 128
  int*   deg      = (int*)(gcnt + 128);        // N
  int*   offs     = deg + Nn;                  // N+64
  int*   cursor   = offs + Nn + 64;            // N
  int*   bsum     = cursor + Nn;               // 64
  int*   carry    = bsum + 64;                 // 64
  unsigned int* epk = (unsigned int*)(carry + 64); // E (4B packed edges)
  __bf16* wtHi    = (__bf16*)(epk + Ee);       // 6*16384 bf16
  __bf16* wtLo    = wtHi + 6 * 16384;          // 6*16384 bf16
  __bf16* xb      = wtLo + 6 * 16384;          // N*128 bf16 (12.8 MB)
  __bf16* aggb    = xb + Nn * 128;             // N*128 bf16
  __bf16* h1b     = aggb + Nn * 128;           // N*128 bf16

  // W prep + x cast + CSR build (once per call, reused by all 3 layers)
  k_wprep<<<48, 256, 0, stream>>>(W1, W2, wtHi, wtLo);
  k_xcast<<<2048, 256, 0, stream>>>(x, xb);
  hipMemsetAsync(deg, 0, Nn * sizeof(int), stream);
  k_deg<<<(Ee / 4 + 255) / 256, 256, 0, stream>>>(dstp, deg);
  k_scan1<<<NSCB, 1024, 0, stream>>>(deg, offs, bsum);
  k_scan2<<<1, 64, 0, stream>>>(bsum, carry);
  k_scan3<<<NSCB, 1024, 0, stream>>>(carry, offs, cursor);
  k_fill<<<(Ee / 4 + 255) / 256, 256, 0, stream>>>(src, dstp, ecn, cursor, epk);

  // bf16 activation streams end-to-end: xb (layer in/out), aggb, h1b.
  for (int l = 0; l < Ll; ++l) {
    k_agg<<<(Nn + 3) / 4, 256, 0, stream>>>(xb, offs, epk, aggb);
    k_gemm1<<<NBLK1, 256, 0, stream>>>(aggb, ncn, xb,
                                       wtHi + l * 16384, wtLo + l * 16384,
                                       b1 + l * 128, h1b, partial);
    k_bnfin<<<128, 256, 0, stream>>>(partial, g1 + l * 128, be1 + l * 128,
                                     scaleA, shiftA);
    k_gemm2<<<NBLK1, 256, 0, stream>>>(h1b, scaleA, shiftA,
                                       wtHi + (3 + l) * 16384, wtLo + (3 + l) * 16384,
                                       b2 + l * 128, xb);
  }

  hipMemsetAsync(pooled, 0, (Gg * 128 + 128) * sizeof(float), stream);
  k_pool<<<(Nn + PCH * 4 - 1) / (PCH * 4), 256, 0, stream>>>(xb, batch, pooled, gcnt);
  k_head<<<Gg, 128, 0, stream>>>(pooled, gcnt, Wc, bc, (float*)d_out);
}